// Round 1
// baseline (5736.473 us; speedup 1.0000x reference)
//
#include <hip/hip_runtime.h>
#include <math.h>

#define BATCH   16384
#define DIMS    64
#define WID     128
#define KN      8
#define NP      23        // 3*KN - 1
#define NLAYERS 8
#define BT      32        // batch rows per block
#define BI_F    4.0f

#define PF_WOUT (NLAYERS * DIMS * NP * WID)   // per-flow masked Wout elems: 1,507,328
#define PF_W1   (NLAYERS * WID * DIMS)        // per-flow masked W1 elems:   65,536

// ---------------------------------------------------------------------------
// Pre-mask the MADE weights into workspace (masks are pure index functions).
// womask layout: [flow][layer][o][h], w1mask layout: [flow][layer][w][i]
// ---------------------------------------------------------------------------
__global__ __launch_bounds__(256) void premask_kernel(
    const float* __restrict__ f_wout, const float* __restrict__ g_wout,
    const float* __restrict__ f_w1,   const float* __restrict__ g_w1,
    float* __restrict__ womask, float* __restrict__ w1mask)
{
    const int idx    = blockIdx.x * 256 + threadIdx.x;
    const int stride = gridDim.x * 256;

    const int totw = 2 * PF_WOUT;
    for (int i = idx; i < totw; i += stride) {
        int fl = i / PF_WOUT;
        int r  = i % PF_WOUT;
        int h  = r % WID;
        int o  = (r / WID) % (DIMS * NP);
        int d  = o / NP;
        int hd = h % (DIMS - 1) + 1;            // hid_deg
        const float* src = fl ? g_wout : f_wout;
        womask[i] = (hd <= d) ? src[r] : 0.0f;  // m2: out_deg(d+1) > hid_deg
    }

    const int tot1 = 2 * PF_W1;
    for (int i = idx; i < tot1; i += stride) {
        int fl = i / PF_W1;
        int r  = i % PF_W1;
        int c  = r % DIMS;
        int w  = (r / DIMS) % WID;
        int deg = w % (DIMS - 1) + 1;           // hid_deg
        const float* src = fl ? g_w1 : f_w1;
        w1mask[i] = (c < deg) ? src[r] : 0.0f;  // m1: hid_deg >= in_deg(c+1)
    }
}

__device__ __forceinline__ float softplusf(float v) {
    return fmaxf(v, 0.0f) + log1pf(expf(-fabsf(v)));
}

// ---------------------------------------------------------------------------
// One MAF layer, both flows (blockIdx.y). BT=32 batch rows per block.
// Phase 1: x tile -> LDS. Phase 2: hidden (64->128, ReLU) -> LDS (transposed).
// Phase 3: thread-per-(b,d): 23-wide dot over 128 h, then RQS spline in regs.
// Output written reversed (x2[:, ::-1]); ld accumulated block-locally.
// ---------------------------------------------------------------------------
__global__ __launch_bounds__(256) void layer_kernel(
    const float* __restrict__ xin_f, const float* __restrict__ xin_g,
    float* __restrict__ xout_f,      float* __restrict__ xout_g,
    const float* __restrict__ w1m_f, const float* __restrict__ w1m_g,
    const float* __restrict__ b1_f,  const float* __restrict__ b1_g,
    const float* __restrict__ wom_f, const float* __restrict__ wom_g,
    const float* __restrict__ bo_f,  const float* __restrict__ bo_g,
    float* __restrict__ ld_f,        float* __restrict__ ld_g,
    int layer)
{
    // xs pitch 68: rows 16B-aligned for float4 LDS reads (phase 2 broadcast).
    __shared__ __align__(16) float xs[BT][68];
    // hsT pitch 33: conflict-free b32 reads across b lanes in phase 3.
    __shared__ float hsT[WID][BT + 1];
    __shared__ float ldred[8][BT];

    const int t     = threadIdx.x;
    const int flow  = blockIdx.y;
    const int brow0 = blockIdx.x * BT;

    const float* xin = flow ? xin_g : xin_f;
    float*      xout = flow ? xout_g : xout_f;
    const float* w1m = flow ? w1m_g : w1m_f;
    const float* b1  = flow ? b1_g  : b1_f;
    const float* wom = flow ? wom_g : wom_f;
    const float* bo  = flow ? bo_g  : bo_f;
    float*       ldp = flow ? ld_g  : ld_f;

    // ---- phase 1: stage x tile ----
    for (int i = t; i < BT * DIMS; i += 256) {
        int b = i >> 6, c = i & 63;
        xs[b][c] = xin[(size_t)(brow0 + b) * DIMS + c];
    }
    __syncthreads();

    // ---- phase 2: hidden layer, thread (b0 = t>>7, w = t&127) ----
    {
        const int w = t & (WID - 1);
        const float bias = b1[w];
        const float* wr = w1m + w * DIMS;
        float wreg[DIMS];
        #pragma unroll
        for (int i = 0; i < DIMS; i += 4) {
            float4 v = *(const float4*)(wr + i);
            wreg[i] = v.x; wreg[i + 1] = v.y; wreg[i + 2] = v.z; wreg[i + 3] = v.w;
        }
        for (int b = (t >> 7); b < BT; b += 2) {
            float acc = bias;
            #pragma unroll
            for (int i = 0; i < DIMS; i += 4) {
                float4 xv = *(const float4*)&xs[b][i];   // wave-uniform -> broadcast
                acc = fmaf(wreg[i],     xv.x, acc);
                acc = fmaf(wreg[i + 1], xv.y, acc);
                acc = fmaf(wreg[i + 2], xv.z, acc);
                acc = fmaf(wreg[i + 3], xv.w, acc);
            }
            hsT[w][b] = fmaxf(acc, 0.0f);
        }
    }
    __syncthreads();

    // ---- phase 3: GEMM2 + spline, thread-per-(b, d) ----
    {
        const int b     = t & (BT - 1);
        const int dbase = t >> 5;              // 0..7; 32 lanes share d -> bcast W loads
        float ldsum = 0.0f;

        #pragma unroll 1
        for (int it = 0; it < 8; ++it) {
            const int d = it * 8 + dbase;
            const float* wrow  = wom + (size_t)d * NP * WID;
            const float* borow = bo + d * NP;

            float acc[NP];
            #pragma unroll
            for (int j = 0; j < NP; ++j) acc[j] = borow[j];

            for (int h0 = 0; h0 < WID; h0 += 4) {
                const float hv0 = hsT[h0][b];
                const float hv1 = hsT[h0 + 1][b];
                const float hv2 = hsT[h0 + 2][b];
                const float hv3 = hsT[h0 + 3][b];
                #pragma unroll
                for (int j = 0; j < NP; ++j) {
                    float4 wv = *(const float4*)(wrow + j * WID + h0);
                    acc[j] = fmaf(wv.x, hv0, acc[j]);
                    acc[j] = fmaf(wv.y, hv1, acc[j]);
                    acc[j] = fmaf(wv.z, hv2, acc[j]);
                    acc[j] = fmaf(wv.w, hv3, acc[j]);
                }
            }

            // ---- RQS spline, all in registers ----
            const float xraw = xs[b][d];

            float mw = acc[0], mh = acc[8];
            #pragma unroll
            for (int j = 1; j < KN; ++j) {
                mw = fmaxf(mw, acc[j]);
                mh = fmaxf(mh, acc[8 + j]);
            }
            float ew[KN], eh[KN];
            float sw = 0.0f, sh = 0.0f;
            #pragma unroll
            for (int j = 0; j < KN; ++j) {
                ew[j] = expf(acc[j] - mw);      sw += ew[j];
                eh[j] = expf(acc[8 + j] - mh);  sh += eh[j];
            }
            const float cmul = 8.0f / 1.01f;    // (p + adj)/(1+ADJ) * 2*Bi
            const float rw = 1.0f / sw, rh = 1.0f / sh;
            float width[KN], height[KN];
            #pragma unroll
            for (int j = 0; j < KN; ++j) {
                width[j]  = (ew[j] * rw + 0.00125f) * cmul;
                height[j] = (eh[j] * rh + 0.00125f) * cmul;
            }
            float dv[KN + 1];
            dv[0] = 1.0f; dv[KN] = 1.0f;
            #pragma unroll
            for (int i = 1; i < KN; ++i) dv[i] = softplusf(acc[15 + i]) + 0.001f;

            const bool inside = (xraw > -BI_F) && (xraw < BI_F);
            const float xcl = fminf(fmaxf(xraw, -BI_F), BI_F);

            // bin select: largest i with x_pos[i] <= xcl (i=0 always true)
            float cx = -BI_F, cy = -BI_F;
            float xk = -BI_F, yk = -BI_F, xk1 = 0.f, yk1 = 0.f, dk = 1.f, dk1 = 1.f;
            #pragma unroll
            for (int i = 0; i < KN; ++i) {
                const float nx = cx + width[i];
                const float ny = cy + height[i];
                const bool c = (xcl >= cx);
                xk  = c ? cx : xk;    yk  = c ? cy : yk;
                xk1 = c ? nx : xk1;   yk1 = c ? ny : yk1;
                dk  = c ? dv[i] : dk; dk1 = c ? dv[i + 1] : dk1;
                cx = nx; cy = ny;
            }

            const float invw = 1.0f / (xk1 - xk);
            const float sk   = (yk1 - yk) * invw;
            const float xi   = (xcl - xk) * invw;
            const float omx  = 1.0f - xi;
            const float den  = sk + (dk1 + dk - 2.0f * sk) * xi * omx;
            float outv = yk + (yk1 - yk) * (sk * xi * xi + dk * xi * omx) / den;
            const float numl = dk1 * xi * xi + 2.0f * sk * xi * omx + dk * omx * omx;
            float ldj = 2.0f * logf(sk) + logf(numl) - 2.0f * logf(den);
            outv = inside ? outv : xraw;
            ldj  = inside ? ldj : 0.0f;

            // write reversed: x2[:, ::-1]
            xout[(size_t)(brow0 + b) * DIMS + (DIMS - 1 - d)] = outv;
            ldsum += ldj;
        }
        ldred[dbase][b] = ldsum;
    }
    __syncthreads();

    // ---- ld reduction: one block owns each batch row -> no atomics ----
    if (t < BT) {
        float s = 0.0f;
        #pragma unroll
        for (int g = 0; g < 8; ++g) s += ldred[g][t];
        const int bg = brow0 + t;
        if (layer == 0) ldp[bg] = s;       // overwrite 0xAA poison
        else            ldp[bg] += s;      // exclusive owner, stream-serialized
    }
}

// ---------------------------------------------------------------------------
extern "C" void kernel_launch(void* const* d_in, const int* in_sizes, int n_in,
                              void* d_out, int out_size, void* d_ws, size_t ws_size,
                              hipStream_t stream)
{
    const float* x      = (const float*)d_in[0];
    const float* y      = (const float*)d_in[1];
    const float* f_W1   = (const float*)d_in[2];
    const float* f_b1   = (const float*)d_in[3];
    const float* f_Wout = (const float*)d_in[4];
    const float* f_bout = (const float*)d_in[5];
    const float* g_W1   = (const float*)d_in[6];
    const float* g_b1   = (const float*)d_in[7];
    const float* g_Wout = (const float*)d_in[8];
    const float* g_bout = (const float*)d_in[9];

    float* out = (float*)d_out;
    float* xo  = out;                               // [B, D]
    float* ldf = out + (size_t)BATCH * DIMS;        // [B]
    float* yo  = ldf + BATCH;                       // [B, D]
    float* ldg = yo + (size_t)BATCH * DIMS;         // [B]

    float* ws     = (float*)d_ws;
    float* womask = ws;                             // 2 * PF_WOUT floats
    float* w1mask = womask + 2 * (size_t)PF_WOUT;   // 2 * PF_W1 floats
    float* xA_f   = w1mask + 2 * (size_t)PF_W1;     // [B, D] ping buffer (f)
    float* xA_g   = xA_f + (size_t)BATCH * DIMS;    // [B, D] ping buffer (g)
    // total ws use: ~20 MB

    premask_kernel<<<dim3(2048), dim3(256), 0, stream>>>(
        f_Wout, g_Wout, f_W1, g_W1, womask, w1mask);

    for (int l = 0; l < NLAYERS; ++l) {
        // even layers write ws ping; odd layers write d_out sections,
        // so layer 7 (odd) lands directly in d_out.
        const float* inf = (l == 0) ? x : ((l & 1) ? xA_f : xo);
        const float* ing = (l == 0) ? y : ((l & 1) ? xA_g : yo);
        float* outf = (l & 1) ? xo : xA_f;
        float* outg = (l & 1) ? yo : xA_g;

        layer_kernel<<<dim3(BATCH / BT, 2), dim3(256), 0, stream>>>(
            inf, ing, outf, outg,
            w1mask + (size_t)l * WID * DIMS,
            w1mask + (size_t)PF_W1 + (size_t)l * WID * DIMS,
            f_b1 + (size_t)l * WID, g_b1 + (size_t)l * WID,
            womask + (size_t)l * DIMS * NP * WID,
            womask + (size_t)PF_WOUT + (size_t)l * DIMS * NP * WID,
            f_bout + (size_t)l * DIMS * NP, g_bout + (size_t)l * DIMS * NP,
            ldf, ldg, l);
    }
}

// Round 2
// 890.420 us; speedup vs baseline: 6.4424x; 6.4424x over previous
//
#include <hip/hip_runtime.h>
#include <math.h>

#define BATCH   16384
#define DIMS    64
#define WID     128
#define KN      8
#define NP      23        // 3*KN - 1
#define NCOL    (DIMS * NP)   // 1472 param columns
#define NLAYERS 8
#define BI_F    4.0f

#define PF_WOUT (NLAYERS * NCOL * WID)        // per-flow Wout elems: 1,507,328
#define PF_W1   (NLAYERS * WID * DIMS)        // per-flow W1 elems:   65,536

typedef short s16x8 __attribute__((ext_vector_type(8)));
typedef float f32x4 __attribute__((ext_vector_type(4)));

__device__ __forceinline__ unsigned short f2bf(float f) {
    unsigned int u = __builtin_bit_cast(unsigned int, f);
    unsigned int r = (u + 0x7FFFu + ((u >> 16) & 1u)) >> 16;
    return (unsigned short)r;
}
__device__ __forceinline__ float bf2f(unsigned short u) {
    return __builtin_bit_cast(float, (unsigned int)u << 16);
}
__device__ __forceinline__ float softplusf(float v) {
    return fmaxf(v, 0.0f) + __logf(1.0f + __expf(-fabsf(v)));
}

// ---------------------------------------------------------------------------
// Pre-mask MADE weights -> bf16 workspace (masks are pure index functions).
// womask: [flow][layer][p=d*23+j][h] ; w1mask: [flow][layer][w][i]
// ---------------------------------------------------------------------------
__global__ __launch_bounds__(256) void premask_kernel(
    const float* __restrict__ f_wout, const float* __restrict__ g_wout,
    const float* __restrict__ f_w1,   const float* __restrict__ g_w1,
    unsigned short* __restrict__ womask, unsigned short* __restrict__ w1mask)
{
    const int idx    = blockIdx.x * 256 + threadIdx.x;
    const int stride = gridDim.x * 256;

    const int totw = 2 * PF_WOUT;
    for (int i = idx; i < totw; i += stride) {
        int fl = i / PF_WOUT;
        int r  = i % PF_WOUT;
        int h  = r % WID;
        int o  = (r / WID) % NCOL;
        int d  = o / NP;
        int hd = h % (DIMS - 1) + 1;            // hid_deg
        const float* src = fl ? g_wout : f_wout;
        womask[i] = (hd <= d) ? f2bf(src[r]) : (unsigned short)0;
    }

    const int tot1 = 2 * PF_W1;
    for (int i = idx; i < tot1; i += stride) {
        int fl = i / PF_W1;
        int r  = i % PF_W1;
        int c  = r % DIMS;
        int w  = (r / DIMS) % WID;
        int deg = w % (DIMS - 1) + 1;           // hid_deg
        const float* src = fl ? g_w1 : f_w1;
        w1mask[i] = (c < deg) ? f2bf(src[r]) : (unsigned short)0;
    }
}

// ---------------------------------------------------------------------------
// One MAF layer, both flows (blockIdx.y). Block = 4 waves, 64 batch rows.
// Each wave owns 16 rows; NO barriers (all dataflow wave-private).
//   GEMM1 (MFMA 16x16x32): H = relu(x @ W1m^T + b1) -> LDS Hs (row-major)
//   GEMM2: 4 chunks x 23 N-tiles, acc in regs, P -> LDS Pcm (col-major bf16)
//   Spline: per (b,d) in registers, reading 23 params from Pcm.
// ---------------------------------------------------------------------------
__global__ __launch_bounds__(256, 2) void layer_kernel(
    const float* __restrict__ xin_f, const float* __restrict__ xin_g,
    float* __restrict__ xout_f,      float* __restrict__ xout_g,
    const unsigned short* __restrict__ w1m_f, const unsigned short* __restrict__ w1m_g,
    const float* __restrict__ b1_f,  const float* __restrict__ b1_g,
    const unsigned short* __restrict__ wom_f, const unsigned short* __restrict__ wom_g,
    const float* __restrict__ bo_f,  const float* __restrict__ bo_g,
    float* __restrict__ ld_f,        float* __restrict__ ld_g,
    int layer)
{
    // Hs: H tile, row-major [batch m][h], pitch 136 (272B: 16B-aligned rows)
    __shared__ __align__(16) unsigned short Hs[4][16][136];
    // Pcm: P tile, column-major [col][row], 368 cols x 16 rows per wave.
    //  write: b64 packed (rows consecutive); read: conflict-free (bank math).
    __shared__ __align__(16) unsigned short Pcm[4][368 * 16];

    const int t    = threadIdx.x;
    const int wv   = t >> 6;          // wave 0..3
    const int ln   = t & 63;
    const int m    = ln & 15;         // row-in-tile / col-in-tile index
    const int q    = ln >> 4;         // quad
    const int flow = blockIdx.y;
    const int r0   = blockIdx.x * 64 + wv * 16;   // this wave's first batch row

    const float* xin          = flow ? xin_g : xin_f;
    float*       xout         = flow ? xout_g : xout_f;
    const unsigned short* w1m = flow ? w1m_g : w1m_f;
    const float* b1           = flow ? b1_g  : b1_f;
    const unsigned short* wom = flow ? wom_g : wom_f;
    const float* bo           = flow ? bo_g  : bo_f;
    float*       ldp          = flow ? ld_g  : ld_f;

    // ---- GEMM1: A-frags from x (global, fp32 -> bf16) ----
    const float* xrow = xin + (size_t)(r0 + m) * DIMS;
    s16x8 xa[2];
    #pragma unroll
    for (int ks = 0; ks < 2; ++ks) {
        float4 v0 = *(const float4*)(xrow + ks * 32 + q * 8);
        float4 v1 = *(const float4*)(xrow + ks * 32 + q * 8 + 4);
        s16x8 a;
        a[0] = (short)f2bf(v0.x); a[1] = (short)f2bf(v0.y);
        a[2] = (short)f2bf(v0.z); a[3] = (short)f2bf(v0.w);
        a[4] = (short)f2bf(v1.x); a[5] = (short)f2bf(v1.y);
        a[6] = (short)f2bf(v1.z); a[7] = (short)f2bf(v1.w);
        xa[ks] = a;
    }

    f32x4 hacc[8];
    #pragma unroll
    for (int nt = 0; nt < 8; ++nt) {
        float bv = b1[nt * 16 + m];
        hacc[nt] = (f32x4){bv, bv, bv, bv};
    }
    #pragma unroll
    for (int ks = 0; ks < 2; ++ks) {
        #pragma unroll
        for (int nt = 0; nt < 8; ++nt) {
            s16x8 bfr = *(const s16x8*)(w1m + (nt * 16 + m) * DIMS + ks * 32 + q * 8);
            hacc[nt] = __builtin_amdgcn_mfma_f32_16x16x32_bf16(xa[ks], bfr, hacc[nt], 0, 0, 0);
        }
    }
    // ReLU -> bf16 -> Hs. Lane holds col (h = nt*16+m), rows q*4+rr.
    #pragma unroll
    for (int nt = 0; nt < 8; ++nt) {
        #pragma unroll
        for (int rr = 0; rr < 4; ++rr) {
            Hs[wv][q * 4 + rr][nt * 16 + m] = f2bf(fmaxf(hacc[nt][rr], 0.0f));
        }
    }

    // ---- A-frags for GEMM2 from Hs (b128 reads, wave-private -> no barrier) ----
    s16x8 af[4];
    #pragma unroll
    for (int ks = 0; ks < 4; ++ks)
        af[ks] = *(const s16x8*)&Hs[wv][m][ks * 32 + q * 8];

    float ldsum = 0.0f;
    unsigned short* pcm = &Pcm[wv][0];

    #pragma unroll 1
    for (int c = 0; c < 4; ++c) {
        // ---- GEMM2 chunk: param cols [c*368, c*368+368) = dims [c*16, c*16+16) ----
        f32x4 acc[23];
        #pragma unroll
        for (int nt = 0; nt < 23; ++nt) {
            float bv = bo[c * 368 + nt * 16 + m];
            acc[nt] = (f32x4){bv, bv, bv, bv};
        }
        #pragma unroll
        for (int ks = 0; ks < 4; ++ks) {
            #pragma unroll
            for (int nt = 0; nt < 23; ++nt) {
                const s16x8 bfr = *(const s16x8*)(wom +
                    (size_t)(c * 368 + nt * 16 + m) * WID + ks * 32 + q * 8);
                acc[nt] = __builtin_amdgcn_mfma_f32_16x16x32_bf16(af[ks], bfr, acc[nt], 0, 0, 0);
            }
        }
        // P -> Pcm column-major: lane col = nt*16+m, rows q*4..q*4+3 consecutive.
        #pragma unroll
        for (int nt = 0; nt < 23; ++nt) {
            unsigned int u0 = (unsigned)f2bf(acc[nt][0]) | ((unsigned)f2bf(acc[nt][1]) << 16);
            unsigned int u1 = (unsigned)f2bf(acc[nt][2]) | ((unsigned)f2bf(acc[nt][3]) << 16);
            uint2 uu; uu.x = u0; uu.y = u1;
            *(uint2*)(pcm + (nt * 16 + m) * 16 + q * 4) = uu;
        }

        // ---- spline: 16 dims x 16 rows, lane=(b=m, dgroup=q), 4 sub-iters ----
        for (int sub = 0; sub < 4; ++sub) {
            const int dl = sub * 4 + q;          // dim within chunk
            const int d  = c * 16 + dl;          // global dim
            const int b  = m;                    // row within wave

            float pp[NP];
            #pragma unroll
            for (int j = 0; j < NP; ++j)
                pp[j] = bf2f(pcm[(dl * NP + j) * 16 + b]);

            const float xraw = xin[(size_t)(r0 + b) * DIMS + d];

            float mw = pp[0], mh = pp[8];
            #pragma unroll
            for (int j = 1; j < KN; ++j) {
                mw = fmaxf(mw, pp[j]);
                mh = fmaxf(mh, pp[8 + j]);
            }
            float ew[KN], eh[KN];
            float sw = 0.0f, sh = 0.0f;
            #pragma unroll
            for (int j = 0; j < KN; ++j) {
                ew[j] = __expf(pp[j] - mw);      sw += ew[j];
                eh[j] = __expf(pp[8 + j] - mh);  sh += eh[j];
            }
            const float cmul = 8.0f / 1.01f;     // 2*Bi/(1+ADJ)
            const float rw = 1.0f / sw, rh = 1.0f / sh;
            float width[KN], height[KN];
            #pragma unroll
            for (int j = 0; j < KN; ++j) {
                width[j]  = (ew[j] * rw + 0.00125f) * cmul;
                height[j] = (eh[j] * rh + 0.00125f) * cmul;
            }
            float dv[KN + 1];
            dv[0] = 1.0f; dv[KN] = 1.0f;
            #pragma unroll
            for (int i = 1; i < KN; ++i) dv[i] = softplusf(pp[15 + i]) + 0.001f;

            const bool inside = (xraw > -BI_F) && (xraw < BI_F);
            const float xcl = fminf(fmaxf(xraw, -BI_F), BI_F);

            float cx = -BI_F, cy = -BI_F;
            float xk = -BI_F, yk = -BI_F, xk1 = 0.f, yk1 = 0.f, dk = 1.f, dk1 = 1.f;
            #pragma unroll
            for (int i = 0; i < KN; ++i) {
                const float nx = cx + width[i];
                const float ny = cy + height[i];
                const bool cc = (xcl >= cx);
                xk  = cc ? cx : xk;    yk  = cc ? cy : yk;
                xk1 = cc ? nx : xk1;   yk1 = cc ? ny : yk1;
                dk  = cc ? dv[i] : dk; dk1 = cc ? dv[i + 1] : dk1;
                cx = nx; cy = ny;
            }

            const float invw = 1.0f / (xk1 - xk);
            const float sk   = (yk1 - yk) * invw;
            const float xi   = (xcl - xk) * invw;
            const float omx  = 1.0f - xi;
            const float den  = sk + (dk1 + dk - 2.0f * sk) * xi * omx;
            float outv = yk + (yk1 - yk) * (sk * xi * xi + dk * xi * omx) / den;
            const float numl = dk1 * xi * xi + 2.0f * sk * xi * omx + dk * omx * omx;
            float ldj = 2.0f * __logf(sk) + __logf(numl) - 2.0f * __logf(den);
            outv = inside ? outv : xraw;
            ldj  = inside ? ldj : 0.0f;

            xout[(size_t)(r0 + b) * DIMS + (DIMS - 1 - d)] = outv;
            ldsum += ldj;
        }
    }

    // ---- ld reduce across the 4 lanes sharing each b (q=0..3) ----
    float v = ldsum + __shfl_xor(ldsum, 16, 64);
    v = v + __shfl_xor(v, 32, 64);
    if (ln < 16) {
        const int bg = r0 + ln;
        if (layer == 0) ldp[bg] = v;    // overwrite poison
        else            ldp[bg] += v;   // exclusive owner, stream-serialized
    }
}

// ---------------------------------------------------------------------------
extern "C" void kernel_launch(void* const* d_in, const int* in_sizes, int n_in,
                              void* d_out, int out_size, void* d_ws, size_t ws_size,
                              hipStream_t stream)
{
    const float* x      = (const float*)d_in[0];
    const float* y      = (const float*)d_in[1];
    const float* f_W1   = (const float*)d_in[2];
    const float* f_b1   = (const float*)d_in[3];
    const float* f_Wout = (const float*)d_in[4];
    const float* f_bout = (const float*)d_in[5];
    const float* g_W1   = (const float*)d_in[6];
    const float* g_b1   = (const float*)d_in[7];
    const float* g_Wout = (const float*)d_in[8];
    const float* g_bout = (const float*)d_in[9];

    float* out = (float*)d_out;
    float* xo  = out;                               // [B, D]
    float* ldf = out + (size_t)BATCH * DIMS;        // [B]
    float* yo  = ldf + BATCH;                       // [B, D]
    float* ldg = yo + (size_t)BATCH * DIMS;         // [B]

    unsigned short* womask = (unsigned short*)d_ws;           // 2*PF_WOUT bf16
    unsigned short* w1mask = womask + 2 * (size_t)PF_WOUT;    // 2*PF_W1 bf16
    float* xA_f = (float*)(w1mask + 2 * (size_t)PF_W1);       // [B,D] ping (f)
    float* xA_g = xA_f + (size_t)BATCH * DIMS;                // [B,D] ping (g)

    premask_kernel<<<dim3(2048), dim3(256), 0, stream>>>(
        f_Wout, g_Wout, f_W1, g_W1, womask, w1mask);

    for (int l = 0; l < NLAYERS; ++l) {
        const float* inf = (l == 0) ? x : ((l & 1) ? xA_f : xo);
        const float* ing = (l == 0) ? y : ((l & 1) ? xA_g : yo);
        float* outf = (l & 1) ? xo : xA_f;
        float* outg = (l & 1) ? yo : xA_g;

        layer_kernel<<<dim3(BATCH / 64, 2), dim3(256), 0, stream>>>(
            inf, ing, outf, outg,
            w1mask + (size_t)l * WID * DIMS,
            w1mask + (size_t)PF_W1 + (size_t)l * WID * DIMS,
            f_b1 + (size_t)l * WID, g_b1 + (size_t)l * WID,
            womask + (size_t)l * NCOL * WID,
            womask + (size_t)PF_WOUT + (size_t)l * NCOL * WID,
            f_bout + (size_t)l * NCOL, g_bout + (size_t)l * NCOL,
            ldf, ldg, l);
    }
}